// Round 7
// baseline (2215.247 us; speedup 1.0000x reference)
//
#include <hip/hip_runtime.h>
#include <hip/hip_bf16.h>

typedef __attribute__((ext_vector_type(8))) short bf16x8;
typedef __attribute__((ext_vector_type(4))) float f32x4;

#define NITER 100
#define WS_SCAL  5904
#define WS_TT    6016                 // float2[NITER]
#define WS_A     8192                 // float A[192*200]
#define WS_FLOATS (8192 + 192*200)
#define BUF1 6144                     // bytes per bounce buffer (16 cols * 384)

__device__ __forceinline__ unsigned short f2bf(float x) {  // RNE
  unsigned u = __builtin_bit_cast(unsigned, x);
  u += 0x7fffu + ((u >> 16) & 1u);
  return (unsigned short)(u >> 16);
}
__device__ __forceinline__ float bf2f(unsigned short h) {
  unsigned u = ((unsigned)h) << 16;
  return __builtin_bit_cast(float, u);
}
__device__ __forceinline__ float ubit(unsigned u) { return __builtin_bit_cast(float, u); }
__device__ __forceinline__ unsigned cvt_pk_bf16(float a, float b) {
  unsigned r;
  asm("v_cvt_pk_bf16_f32 %0, %1, %2" : "=v"(r) : "v"(a), "v"(b));
  return r;
}

// ---------------- prep: D (normalized), linv/lambd, tt table, A (float) -> ws ----------------
__global__ __launch_bounds__(256) void prep_kernel(const float* __restrict__ Drr,
                                                   const float* __restrict__ Dth,
                                                   float* __restrict__ ws)
{
  __shared__ float sD[36 * 164];
  __shared__ float sIG[164];
  __shared__ float sRed[256];
  const int tid = (int)threadIdx.x;

  for (int idx = tid; idx < 36 * 164; idx += 256) {
    int t = idx / 164, k = idx - t * 164;
    float v = 0.0f;
    if (k == 0) v = 1.0f;
    else if (k < 161) {
      int km = k - 1, g = km / 40, n = km - g * 40;
      float pw  = powf(Drr[n], (float)t);
      float ang = (float)t * Dth[n];
      float base = ((g & 2) == 0) ? cosf(ang) : sinf(ang);
      v = pw * base;
      if ((g & 1) && (t & 1)) v = -v;
    }
    sD[idx] = v;
  }
  __syncthreads();
  if (tid < 161) {
    float s = 0.0f;
    for (int t = 0; t < 36; ++t) { float d = sD[t * 164 + tid]; s += d * d; }
    float g = sqrtf(s);
    if (g == 0.0f) g = 6.0f;
    sIG[tid] = 1.0f / g;
  }
  __syncthreads();
  for (int idx = tid; idx < 36 * 164; idx += 256) {
    int k = idx % 164;
    if (k < 161) sD[idx] *= sIG[k];
  }
  __syncthreads();
  {  // L = ||DtD||_F = ||D D^T||_F (36x36 gram)
    float local = 0.0f;
    for (int idx = tid; idx < 36 * 36; idx += 256) {
      int t = idx / 36, t2 = idx - t * 36;
      float dot = 0.0f;
      for (int k = 0; k < 161; ++k) dot += sD[t * 164 + k] * sD[t2 * 164 + k];
      local += dot * dot;
    }
    sRed[tid] = local;
  }
  __syncthreads();
  for (int off = 128; off > 0; off >>= 1) {
    if (tid < off) sRed[tid] += sRed[tid + off];
    __syncthreads();
  }
  const float linv = 1.0f / sqrtf(sRed[0]);

  if (blockIdx.x == 0) {
    for (int idx = tid; idx < 36 * 164; idx += 256) ws[idx] = sD[idx];
    if (tid == 0) {
      ws[WS_SCAL] = linv;
      ws[WS_SCAL + 1] = 0.01f * linv;
      float t = 1.0f;                     // tt table (exact reference recurrence)
      for (int k = 0; k < NITER; ++k) {
        float tn = 0.5f * (1.0f + sqrtf(1.0f + 4.0f * t * t));
        float tt = (t - 1.0f) / tn;
        ws[WS_TT + 2 * k]     = tt;
        ws[WS_TT + 2 * k + 1] = 1.0f + tt;
        t = tn;
      }
    }
  }
  const int ENT = (192 * 200 + (int)gridDim.x - 1) / (int)gridDim.x;
  const int base = (int)blockIdx.x * ENT;
  for (int i = tid; i < ENT; i += 256) {
    int e = base + i;
    if (e >= 192 * 200) break;
    int r = e / 200, j = e - r * 200;
    float a = 0.0f;
    if (r < 161 && j < 161) {
      float dot = 0.0f;
      for (int t = 0; t < 36; ++t) dot += sD[t * 164 + r] * sD[t * 164 + j];
      a = ((r == j) ? 1.0f : 0.0f) - dot * linv;
    }
    ws[WS_A + e] = a;
  }
}

// ---------------- fista: 6 waves x 2 row-tiles, 16 cols/block, 2 blocks/CU ----------------
// Wave w owns rows 32w..32w+31 (12 tiles of 16 cover all 192 padded rows).
// Per-wave regs ~145 (A 96 + P/xe 24 + misc) <= 170 budget at 3 waves/EU -> no spill.
template <int USE_WS>
__global__ __launch_bounds__(384, 3) void fista_kernel(
    const float* __restrict__ X, const float* __restrict__ Drr,
    const float* __restrict__ Dth, float* __restrict__ out,
    const float* __restrict__ ws)
{
  __shared__ union {
    struct { float sD[36 * 164]; float sIG[164]; float sRed[384]; } su;
    struct { unsigned char bounce[2][BUF1]; float2 tt[112]; } lp;
  } sm;
  float* sD = sm.su.sD;

  const int tid  = (int)threadIdx.x;
  const int lane = tid & 63;
  const int wv   = tid >> 6;     // 0..5
  const int cl   = lane & 15;    // column / A-row-in-tile
  const int hi   = lane >> 4;    // 0..3

  float linv, lambd;
  if constexpr (USE_WS) {
    for (int idx = tid; idx < 36 * 164; idx += 384) sD[idx] = ws[idx];
    linv  = ws[WS_SCAL];
    lambd = ws[WS_SCAL + 1];
    __syncthreads();
  } else {
    // -------- in-block fallback (correctness path) --------
    for (int idx = tid; idx < 36 * 164; idx += 384) {
      int t = idx / 164, k = idx - t * 164;
      float v = 0.0f;
      if (k == 0) v = 1.0f;
      else if (k < 161) {
        int km = k - 1, g = km / 40, n = km - g * 40;
        float pw  = powf(Drr[n], (float)t);
        float ang = (float)t * Dth[n];
        float base = ((g & 2) == 0) ? cosf(ang) : sinf(ang);
        v = pw * base;
        if ((g & 1) && (t & 1)) v = -v;
      }
      sD[idx] = v;
    }
    __syncthreads();
    if (tid < 161) {
      float s = 0.0f;
      for (int t = 0; t < 36; ++t) { float d = sD[t * 164 + tid]; s += d * d; }
      float g = sqrtf(s);
      if (g == 0.0f) g = 6.0f;
      sm.su.sIG[tid] = 1.0f / g;
    }
    __syncthreads();
    for (int idx = tid; idx < 36 * 164; idx += 384) {
      int k = idx % 164;
      if (k < 161) sD[idx] *= sm.su.sIG[k];
    }
    __syncthreads();
    {
      float local = 0.0f;
      for (int idx = tid; idx < 36 * 36; idx += 384) {
        int t = idx / 36, t2 = idx - t * 36;
        float dot = 0.0f;
        for (int k = 0; k < 161; ++k) dot += sD[t * 164 + k] * sD[t2 * 164 + k];
        local += dot * dot;
      }
      sm.su.sRed[tid] = local;
    }
    __syncthreads();
    if (tid < 128) sm.su.sRed[tid] += sm.su.sRed[tid + 128] + sm.su.sRed[tid + 256];
    __syncthreads();
    for (int off = 64; off > 0; off >>= 1) {
      if (tid < off) sm.su.sRed[tid] += sm.su.sRed[tid + off];
      __syncthreads();
    }
    linv  = 1.0f / sqrtf(sm.su.sRed[0]);
    lambd = 0.01f * linv;
  }

  // ---------- A fragments (bf16 hi/lo) for tiles {2wv, 2wv+1} ----------
  bf16x8 Ah[2][6], Al[2][6];
  if constexpr (USE_WS) {
    #pragma unroll
    for (int tau = 0; tau < 2; ++tau) {
      const int r = (2 * wv + tau) * 16 + cl;
      #pragma unroll
      for (int kt = 0; kt < 6; ++kt) {
        const float* ap = ws + WS_A + r * 200 + kt * 32 + hi * 8;
        f32x4 a0 = *reinterpret_cast<const f32x4*>(ap);
        f32x4 a1 = *reinterpret_cast<const f32x4*>(ap + 4);
        float av[8] = {a0[0], a0[1], a0[2], a0[3], a1[0], a1[1], a1[2], a1[3]};
        bf16x8 vh, vl;
        #pragma unroll
        for (int j = 0; j < 8; ++j) {
          unsigned short h = f2bf(av[j]);
          vh[j] = (short)h;
          vl[j] = (short)f2bf(av[j] - bf2f(h));
        }
        Ah[tau][kt] = vh;
        Al[tau][kt] = vl;
      }
    }
  } else {
    #pragma unroll
    for (int tau = 0; tau < 2; ++tau) {
      const int r = (2 * wv + tau) * 16 + cl;
      #pragma unroll
      for (int kt = 0; kt < 6; ++kt) {
        const int k0 = kt * 32 + hi * 8;
        float acc8[8];
        #pragma unroll
        for (int j = 0; j < 8; ++j) acc8[j] = 0.0f;
        if (r < 161) {
          for (int t = 0; t < 36; ++t) {
            float vr = sD[t * 164 + r];
            #pragma unroll
            for (int j = 0; j < 8; ++j) acc8[j] += vr * sD[t * 164 + k0 + j];
          }
        }
        bf16x8 vh, vl;
        #pragma unroll
        for (int j = 0; j < 8; ++j) {
          int k = k0 + j;
          float a = 0.0f;
          if (r < 161 && k < 161) {
            a = -acc8[j] * linv;
            if (r == k) a += 1.0f;
          }
          unsigned short h = f2bf(a);
          vh[j] = (short)h;
          vl[j] = (short)f2bf(a - bf2f(h));
        }
        Ah[tau][kt] = vh;
        Al[tau][kt] = vl;
      }
    }
  }

  // ---------- DtY -> P0 (C/D layout: row=(2wv+tau)*16+hi*4+q, col=cl) ----------
  const int c = (int)blockIdx.x * 16 + cl;
  const int b = c >> 14;
  const int p = c & 16383;
  const float* Xc = X + (size_t)b * (36 * 16384) + p;

  f32x4 P0[2], P1[2], xe[2];
  #pragma unroll
  for (int tau = 0; tau < 2; ++tau)
    #pragma unroll
    for (int q = 0; q < 4; ++q) { P0[tau][q] = 0.0f; P1[tau][q] = 0.0f; xe[tau][q] = 0.0f; }

  for (int t = 0; t < 36; ++t) {
    float yv = Xc[(size_t)t * 16384];
    #pragma unroll
    for (int tau = 0; tau < 2; ++tau) {
      f32x4 df = *reinterpret_cast<const f32x4*>(sD + t * 164 + (2 * wv + tau) * 16 + hi * 4);
      #pragma unroll
      for (int q = 0; q < 4; ++q) P0[tau][q] += df[q] * yv;
    }
  }
  #pragma unroll
  for (int tau = 0; tau < 2; ++tau)
    #pragma unroll
    for (int q = 0; q < 4; ++q) {
      int r = (2 * wv + tau) * 16 + hi * 4 + q;
      P0[tau][q] = (r < 161) ? P0[tau][q] * linv : 0.0f;
    }
  __syncthreads();   // sD dead; union becomes {bounce, tt}

  // ---------- tt table into LDS ----------
  if constexpr (USE_WS) {
    const float2* wt = reinterpret_cast<const float2*>(ws + WS_TT);
    for (int i = tid; i < NITER; i += 384) sm.lp.tt[i] = wt[i];
  } else {
    if (tid == 0) {
      float t = 1.0f;
      for (int k = 0; k < NITER; ++k) {
        float tn = 0.5f * (1.0f + sqrtf(1.0f + 4.0f * t * t));
        float tt = (t - 1.0f) / tn;
        sm.lp.tt[k] = make_float2(tt, 1.0f + tt);
        t = tn;
      }
    }
  }
  __syncthreads();

  // ---------- swizzled LDS addresses (loop-invariant) ----------
  unsigned char* colb = &sm.lp.bounce[0][0] + cl * 384;
  const unsigned swz = (unsigned)((cl & 7) << 4);
  unsigned char* rdA[6];
  #pragma unroll
  for (int kt = 0; kt < 6; ++kt)
    rdA[kt] = colb + (((unsigned)(kt * 64 + hi * 16)) ^ swz);
  unsigned char* wrA[2];
  #pragma unroll
  for (int tau = 0; tau < 2; ++tau)
    wrA[tau] = colb + (((unsigned)((2 * wv + tau) * 32 + hi * 8)) ^ swz);

  // ---------- FISTA main loop ----------
  // p tracks A*xe + DtY (xe = running sum of bf16-quantized increments, error feedback).
  // u = (1+tt)p_k - tt p_{k-1}; xn = shrink(u); dq = bf16(xn - xe); xe += dq;
  // p_{k+1} = p_k + (Ah+Al)*dq  (split-precision bf16 MFMA pair).
  auto step = [&](f32x4 (&PC)[2], f32x4 (&PN)[2], int it, int boff) {
    float2 t2 = sm.lp.tt[it];
    const float ttp = t2.x, c1 = t2.y;
    #pragma unroll
    for (int tau = 0; tau < 2; ++tau) {
      float dq_[4];
      #pragma unroll
      for (int q = 0; q < 4; ++q) {
        float u  = c1 * PC[tau][q] - ttp * PN[tau][q];
        float aa = fmaxf(fabsf(u) - lambd, 0.0f);
        float xn = __builtin_copysignf(aa, u);
        dq_[q] = xn - xe[tau][q];
      }
      unsigned w0 = cvt_pk_bf16(dq_[0], dq_[1]);
      unsigned w1 = cvt_pk_bf16(dq_[2], dq_[3]);
      xe[tau][0] += ubit(w0 << 16);
      xe[tau][1] += ubit(w0 & 0xffff0000u);
      xe[tau][2] += ubit(w1 << 16);
      xe[tau][3] += ubit(w1 & 0xffff0000u);
      *reinterpret_cast<uint2*>(wrA[tau] + boff) = make_uint2(w0, w1);
    }
    __syncthreads();   // d visible; double-buffer -> 1 barrier/step
    f32x4 acc0 = PC[0], acc1 = PC[1];
    #pragma unroll
    for (int kt = 0; kt < 6; ++kt) {
      bf16x8 bh = *reinterpret_cast<const bf16x8*>(rdA[kt] + boff);
      acc0 = __builtin_amdgcn_mfma_f32_16x16x32_bf16(Ah[0][kt], bh, acc0, 0, 0, 0);
      acc0 = __builtin_amdgcn_mfma_f32_16x16x32_bf16(Al[0][kt], bh, acc0, 0, 0, 0);
      acc1 = __builtin_amdgcn_mfma_f32_16x16x32_bf16(Ah[1][kt], bh, acc1, 0, 0, 0);
      acc1 = __builtin_amdgcn_mfma_f32_16x16x32_bf16(Al[1][kt], bh, acc1, 0, 0, 0);
    }
    PN[0] = acc0;      // p_{k+1}
    PN[1] = acc1;
  };

  #pragma unroll 1
  for (int j = 0; j < NITER / 2; ++j) {
    step(P0, P1, 2 * j, 0);
    step(P1, P0, 2 * j + 1, BUF1);
  }

  // ---------- store x (= xe) ----------
  float* op = out + (size_t)b * (161 * 16384) + p;
  #pragma unroll
  for (int tau = 0; tau < 2; ++tau)
    #pragma unroll
    for (int q = 0; q < 4; ++q) {
      int r = (2 * wv + tau) * 16 + hi * 4 + q;
      if (r < 161) op[(size_t)r * 16384] = xe[tau][q];
    }
}

extern "C" void kernel_launch(void* const* d_in, const int* in_sizes, int n_in,
                              void* d_out, int out_size, void* d_ws, size_t ws_size,
                              hipStream_t stream) {
  const float* X   = (const float*)d_in[0];
  const float* Drr = (const float*)d_in[1];
  const float* Dth = (const float*)d_in[2];
  float* out = (float*)d_out;
  (void)in_sizes; (void)n_in; (void)out_size;

  if (ws_size >= (size_t)WS_FLOATS * sizeof(float)) {
    float* ws = (float*)d_ws;
    prep_kernel<<<dim3(64), dim3(256), 0, stream>>>(Drr, Dth, ws);
    fista_kernel<1><<<dim3(4096), dim3(384), 0, stream>>>(X, Drr, Dth, out, ws);
  } else {
    fista_kernel<0><<<dim3(4096), dim3(384), 0, stream>>>(X, Drr, Dth, out, nullptr);
  }
}

// Round 8
// 1824.936 us; speedup vs baseline: 1.2139x; 1.2139x over previous
//
#include <hip/hip_runtime.h>
#include <hip/hip_bf16.h>

typedef __attribute__((ext_vector_type(8))) short bf16x8;
typedef __attribute__((ext_vector_type(4))) float f32x4;

#define NITER 100
#define WS_SCAL  5904
#define WS_TT    6016                 // float2[NITER]
#define WS_A     8192                 // float A[192*200]
#define WS_FLOATS (8192 + 192*200)
#define BUF1 6144                     // bytes per bounce buffer (16 cols * 384)

__device__ __forceinline__ unsigned short f2bf(float x) {  // RNE
  unsigned u = __builtin_bit_cast(unsigned, x);
  u += 0x7fffu + ((u >> 16) & 1u);
  return (unsigned short)(u >> 16);
}
__device__ __forceinline__ float bf2f(unsigned short h) {
  unsigned u = ((unsigned)h) << 16;
  return __builtin_bit_cast(float, u);
}
__device__ __forceinline__ float ubit(unsigned u) { return __builtin_bit_cast(float, u); }
__device__ __forceinline__ unsigned cvt_pk_bf16(float a, float b) {
  unsigned r;
  asm("v_cvt_pk_bf16_f32 %0, %1, %2" : "=v"(r) : "v"(a), "v"(b));
  return r;
}

// ---------------- prep: D (normalized), linv/lambd, tt table, A (float) -> ws ----------------
__global__ __launch_bounds__(256) void prep_kernel(const float* __restrict__ Drr,
                                                   const float* __restrict__ Dth,
                                                   float* __restrict__ ws)
{
  __shared__ float sD[36 * 164];
  __shared__ float sIG[164];
  __shared__ float sRed[256];
  const int tid = (int)threadIdx.x;

  for (int idx = tid; idx < 36 * 164; idx += 256) {
    int t = idx / 164, k = idx - t * 164;
    float v = 0.0f;
    if (k == 0) v = 1.0f;
    else if (k < 161) {
      int km = k - 1, g = km / 40, n = km - g * 40;
      float pw  = powf(Drr[n], (float)t);
      float ang = (float)t * Dth[n];
      float base = ((g & 2) == 0) ? cosf(ang) : sinf(ang);
      v = pw * base;
      if ((g & 1) && (t & 1)) v = -v;
    }
    sD[idx] = v;
  }
  __syncthreads();
  if (tid < 161) {
    float s = 0.0f;
    for (int t = 0; t < 36; ++t) { float d = sD[t * 164 + tid]; s += d * d; }
    float g = sqrtf(s);
    if (g == 0.0f) g = 6.0f;
    sIG[tid] = 1.0f / g;
  }
  __syncthreads();
  for (int idx = tid; idx < 36 * 164; idx += 256) {
    int k = idx % 164;
    if (k < 161) sD[idx] *= sIG[k];
  }
  __syncthreads();
  {  // L = ||DtD||_F = ||D D^T||_F (36x36 gram)
    float local = 0.0f;
    for (int idx = tid; idx < 36 * 36; idx += 256) {
      int t = idx / 36, t2 = idx - t * 36;
      float dot = 0.0f;
      for (int k = 0; k < 161; ++k) dot += sD[t * 164 + k] * sD[t2 * 164 + k];
      local += dot * dot;
    }
    sRed[tid] = local;
  }
  __syncthreads();
  for (int off = 128; off > 0; off >>= 1) {
    if (tid < off) sRed[tid] += sRed[tid + off];
    __syncthreads();
  }
  const float linv = 1.0f / sqrtf(sRed[0]);

  if (blockIdx.x == 0) {
    for (int idx = tid; idx < 36 * 164; idx += 256) ws[idx] = sD[idx];
    if (tid == 0) {
      ws[WS_SCAL] = linv;
      ws[WS_SCAL + 1] = 0.01f * linv;
      float t = 1.0f;                     // tt table (exact reference recurrence)
      for (int k = 0; k < NITER; ++k) {
        float tn = 0.5f * (1.0f + sqrtf(1.0f + 4.0f * t * t));
        float tt = (t - 1.0f) / tn;
        ws[WS_TT + 2 * k]     = tt;
        ws[WS_TT + 2 * k + 1] = 1.0f + tt;
        t = tn;
      }
    }
  }
  const int ENT = (192 * 200 + (int)gridDim.x - 1) / (int)gridDim.x;
  const int base = (int)blockIdx.x * ENT;
  for (int i = tid; i < ENT; i += 256) {
    int e = base + i;
    if (e >= 192 * 200) break;
    int r = e / 200, j = e - r * 200;
    float a = 0.0f;
    if (r < 161 && j < 161) {
      float dot = 0.0f;
      for (int t = 0; t < 36; ++t) dot += sD[t * 164 + r] * sD[t * 164 + j];
      a = ((r == j) ? 1.0f : 0.0f) - dot * linv;
    }
    ws[WS_A + e] = a;
  }
}

// ---------------- fista: 6 waves x 2 row-tiles, 16 cols/block ----------------
// Wave w owns rows 32w..32w+31 (12 tiles of 16 cover all 192 padded rows).
// launch_bounds min-waves MUST be 2: state ~190 regs/wave; requesting 3 (170-reg
// budget) made the allocator spill A-fragments to scratch in-loop (R6/R7: GBs of
// HBM write traffic, 70% slowdown) while HW ran 1 block/CU anyway.
template <int USE_WS>
__global__ __launch_bounds__(384, 2) void fista_kernel(
    const float* __restrict__ X, const float* __restrict__ Drr,
    const float* __restrict__ Dth, float* __restrict__ out,
    const float* __restrict__ ws)
{
  __shared__ union {
    struct { float sD[36 * 164]; float sIG[164]; float sRed[384]; } su;
    struct { unsigned char bounce[2][BUF1]; float2 tt[112]; } lp;
  } sm;
  float* sD = sm.su.sD;

  const int tid  = (int)threadIdx.x;
  const int lane = tid & 63;
  const int wv   = tid >> 6;     // 0..5
  const int cl   = lane & 15;    // column / A-row-in-tile
  const int hi   = lane >> 4;    // 0..3

  float linv, lambd;
  if constexpr (USE_WS) {
    for (int idx = tid; idx < 36 * 164; idx += 384) sD[idx] = ws[idx];
    linv  = ws[WS_SCAL];
    lambd = ws[WS_SCAL + 1];
    __syncthreads();
  } else {
    // -------- in-block fallback (correctness path) --------
    for (int idx = tid; idx < 36 * 164; idx += 384) {
      int t = idx / 164, k = idx - t * 164;
      float v = 0.0f;
      if (k == 0) v = 1.0f;
      else if (k < 161) {
        int km = k - 1, g = km / 40, n = km - g * 40;
        float pw  = powf(Drr[n], (float)t);
        float ang = (float)t * Dth[n];
        float base = ((g & 2) == 0) ? cosf(ang) : sinf(ang);
        v = pw * base;
        if ((g & 1) && (t & 1)) v = -v;
      }
      sD[idx] = v;
    }
    __syncthreads();
    if (tid < 161) {
      float s = 0.0f;
      for (int t = 0; t < 36; ++t) { float d = sD[t * 164 + tid]; s += d * d; }
      float g = sqrtf(s);
      if (g == 0.0f) g = 6.0f;
      sm.su.sIG[tid] = 1.0f / g;
    }
    __syncthreads();
    for (int idx = tid; idx < 36 * 164; idx += 384) {
      int k = idx % 164;
      if (k < 161) sD[idx] *= sm.su.sIG[k];
    }
    __syncthreads();
    {
      float local = 0.0f;
      for (int idx = tid; idx < 36 * 36; idx += 384) {
        int t = idx / 36, t2 = idx - t * 36;
        float dot = 0.0f;
        for (int k = 0; k < 161; ++k) dot += sD[t * 164 + k] * sD[t2 * 164 + k];
        local += dot * dot;
      }
      sm.su.sRed[tid] = local;
    }
    __syncthreads();
    if (tid < 128) sm.su.sRed[tid] += sm.su.sRed[tid + 128] + sm.su.sRed[tid + 256];
    __syncthreads();
    for (int off = 64; off > 0; off >>= 1) {
      if (tid < off) sm.su.sRed[tid] += sm.su.sRed[tid + off];
      __syncthreads();
    }
    linv  = 1.0f / sqrtf(sm.su.sRed[0]);
    lambd = 0.01f * linv;
  }

  // ---------- A fragments (bf16 hi/lo) for tiles {2wv, 2wv+1} ----------
  bf16x8 Ah[2][6], Al[2][6];
  if constexpr (USE_WS) {
    #pragma unroll
    for (int tau = 0; tau < 2; ++tau) {
      const int r = (2 * wv + tau) * 16 + cl;
      #pragma unroll
      for (int kt = 0; kt < 6; ++kt) {
        const float* ap = ws + WS_A + r * 200 + kt * 32 + hi * 8;
        f32x4 a0 = *reinterpret_cast<const f32x4*>(ap);
        f32x4 a1 = *reinterpret_cast<const f32x4*>(ap + 4);
        float av[8] = {a0[0], a0[1], a0[2], a0[3], a1[0], a1[1], a1[2], a1[3]};
        bf16x8 vh, vl;
        #pragma unroll
        for (int j = 0; j < 8; ++j) {
          unsigned short h = f2bf(av[j]);
          vh[j] = (short)h;
          vl[j] = (short)f2bf(av[j] - bf2f(h));
        }
        Ah[tau][kt] = vh;
        Al[tau][kt] = vl;
      }
    }
  } else {
    #pragma unroll
    for (int tau = 0; tau < 2; ++tau) {
      const int r = (2 * wv + tau) * 16 + cl;
      #pragma unroll
      for (int kt = 0; kt < 6; ++kt) {
        const int k0 = kt * 32 + hi * 8;
        float acc8[8];
        #pragma unroll
        for (int j = 0; j < 8; ++j) acc8[j] = 0.0f;
        if (r < 161) {
          for (int t = 0; t < 36; ++t) {
            float vr = sD[t * 164 + r];
            #pragma unroll
            for (int j = 0; j < 8; ++j) acc8[j] += vr * sD[t * 164 + k0 + j];
          }
        }
        bf16x8 vh, vl;
        #pragma unroll
        for (int j = 0; j < 8; ++j) {
          int k = k0 + j;
          float a = 0.0f;
          if (r < 161 && k < 161) {
            a = -acc8[j] * linv;
            if (r == k) a += 1.0f;
          }
          unsigned short h = f2bf(a);
          vh[j] = (short)h;
          vl[j] = (short)f2bf(a - bf2f(h));
        }
        Ah[tau][kt] = vh;
        Al[tau][kt] = vl;
      }
    }
  }

  // ---------- DtY -> P0 (C/D layout: row=(2wv+tau)*16+hi*4+q, col=cl) ----------
  const int c = (int)blockIdx.x * 16 + cl;
  const int b = c >> 14;
  const int p = c & 16383;
  const float* Xc = X + (size_t)b * (36 * 16384) + p;

  f32x4 P0[2], P1[2], xe[2];
  #pragma unroll
  for (int tau = 0; tau < 2; ++tau)
    #pragma unroll
    for (int q = 0; q < 4; ++q) { P0[tau][q] = 0.0f; P1[tau][q] = 0.0f; xe[tau][q] = 0.0f; }

  for (int t = 0; t < 36; ++t) {
    float yv = Xc[(size_t)t * 16384];
    #pragma unroll
    for (int tau = 0; tau < 2; ++tau) {
      f32x4 df = *reinterpret_cast<const f32x4*>(sD + t * 164 + (2 * wv + tau) * 16 + hi * 4);
      #pragma unroll
      for (int q = 0; q < 4; ++q) P0[tau][q] += df[q] * yv;
    }
  }
  #pragma unroll
  for (int tau = 0; tau < 2; ++tau)
    #pragma unroll
    for (int q = 0; q < 4; ++q) {
      int r = (2 * wv + tau) * 16 + hi * 4 + q;
      P0[tau][q] = (r < 161) ? P0[tau][q] * linv : 0.0f;
    }
  __syncthreads();   // sD dead; union becomes {bounce, tt}

  // ---------- tt table into LDS ----------
  if constexpr (USE_WS) {
    const float2* wt = reinterpret_cast<const float2*>(ws + WS_TT);
    for (int i = tid; i < NITER; i += 384) sm.lp.tt[i] = wt[i];
  } else {
    if (tid == 0) {
      float t = 1.0f;
      for (int k = 0; k < NITER; ++k) {
        float tn = 0.5f * (1.0f + sqrtf(1.0f + 4.0f * t * t));
        float tt = (t - 1.0f) / tn;
        sm.lp.tt[k] = make_float2(tt, 1.0f + tt);
        t = tn;
      }
    }
  }
  __syncthreads();

  // ---------- swizzled LDS addresses (loop-invariant) ----------
  unsigned char* colb = &sm.lp.bounce[0][0] + cl * 384;
  const unsigned swz = (unsigned)((cl & 7) << 4);
  unsigned char* rdA[6];
  #pragma unroll
  for (int kt = 0; kt < 6; ++kt)
    rdA[kt] = colb + (((unsigned)(kt * 64 + hi * 16)) ^ swz);
  unsigned char* wrA[2];
  #pragma unroll
  for (int tau = 0; tau < 2; ++tau)
    wrA[tau] = colb + (((unsigned)((2 * wv + tau) * 32 + hi * 8)) ^ swz);

  // ---------- FISTA main loop ----------
  // p tracks A*xe + DtY (xe = running sum of bf16-quantized increments, error feedback).
  // u = (1+tt)p_k - tt p_{k-1}; xn = shrink(u); dq = bf16(xn - xe); xe += dq;
  // p_{k+1} = p_k + (Ah+Al)*dq.
  // MFMA accumulation split into 4 independent chains of depth 6 (accH seeded with
  // p_k, accL seeded 0, summed after) -- halves the dependent-MFMA critical path.
  auto step = [&](f32x4 (&PC)[2], f32x4 (&PN)[2], int it, int boff) {
    float2 t2 = sm.lp.tt[it];
    const float ttp = t2.x, c1 = t2.y;
    #pragma unroll
    for (int tau = 0; tau < 2; ++tau) {
      float dq_[4];
      #pragma unroll
      for (int q = 0; q < 4; ++q) {
        float u  = c1 * PC[tau][q] - ttp * PN[tau][q];
        float aa = fmaxf(fabsf(u) - lambd, 0.0f);
        float xn = __builtin_copysignf(aa, u);
        dq_[q] = xn - xe[tau][q];
      }
      unsigned w0 = cvt_pk_bf16(dq_[0], dq_[1]);
      unsigned w1 = cvt_pk_bf16(dq_[2], dq_[3]);
      xe[tau][0] += ubit(w0 << 16);
      xe[tau][1] += ubit(w0 & 0xffff0000u);
      xe[tau][2] += ubit(w1 << 16);
      xe[tau][3] += ubit(w1 & 0xffff0000u);
      *reinterpret_cast<uint2*>(wrA[tau] + boff) = make_uint2(w0, w1);
    }
    __syncthreads();   // d visible; double-buffer -> 1 barrier/step
    f32x4 aH0 = PC[0], aH1 = PC[1];
    f32x4 aL0 = {0.0f, 0.0f, 0.0f, 0.0f}, aL1 = {0.0f, 0.0f, 0.0f, 0.0f};
    #pragma unroll
    for (int kt = 0; kt < 6; ++kt) {
      bf16x8 bh = *reinterpret_cast<const bf16x8*>(rdA[kt] + boff);
      aH0 = __builtin_amdgcn_mfma_f32_16x16x32_bf16(Ah[0][kt], bh, aH0, 0, 0, 0);
      aL0 = __builtin_amdgcn_mfma_f32_16x16x32_bf16(Al[0][kt], bh, aL0, 0, 0, 0);
      aH1 = __builtin_amdgcn_mfma_f32_16x16x32_bf16(Ah[1][kt], bh, aH1, 0, 0, 0);
      aL1 = __builtin_amdgcn_mfma_f32_16x16x32_bf16(Al[1][kt], bh, aL1, 0, 0, 0);
    }
    #pragma unroll
    for (int q = 0; q < 4; ++q) {
      PN[0][q] = aH0[q] + aL0[q];   // p_{k+1}
      PN[1][q] = aH1[q] + aL1[q];
    }
  };

  #pragma unroll 1
  for (int j = 0; j < NITER / 2; ++j) {
    step(P0, P1, 2 * j, 0);
    step(P1, P0, 2 * j + 1, BUF1);
  }

  // ---------- store x (= xe) ----------
  float* op = out + (size_t)b * (161 * 16384) + p;
  #pragma unroll
  for (int tau = 0; tau < 2; ++tau)
    #pragma unroll
    for (int q = 0; q < 4; ++q) {
      int r = (2 * wv + tau) * 16 + hi * 4 + q;
      if (r < 161) op[(size_t)r * 16384] = xe[tau][q];
    }
}

extern "C" void kernel_launch(void* const* d_in, const int* in_sizes, int n_in,
                              void* d_out, int out_size, void* d_ws, size_t ws_size,
                              hipStream_t stream) {
  const float* X   = (const float*)d_in[0];
  const float* Drr = (const float*)d_in[1];
  const float* Dth = (const float*)d_in[2];
  float* out = (float*)d_out;
  (void)in_sizes; (void)n_in; (void)out_size;

  if (ws_size >= (size_t)WS_FLOATS * sizeof(float)) {
    float* ws = (float*)d_ws;
    prep_kernel<<<dim3(64), dim3(256), 0, stream>>>(Drr, Dth, ws);
    fista_kernel<1><<<dim3(4096), dim3(384), 0, stream>>>(X, Drr, Dth, out, ws);
  } else {
    fista_kernel<0><<<dim3(4096), dim3(384), 0, stream>>>(X, Drr, Dth, out, nullptr);
  }
}

// Round 9
// 1344.994 us; speedup vs baseline: 1.6470x; 1.3568x over previous
//
#include <hip/hip_runtime.h>
#include <hip/hip_bf16.h>

typedef __attribute__((ext_vector_type(8))) short bf16x8;
typedef __attribute__((ext_vector_type(4))) float f32x4;

#define NITER 100
#define MT 2                 // max row-tiles per wave
#define WS_SCAL  5904
#define WS_A     8192
#define WS_FLOATS (8192 + 192*200)

__device__ __forceinline__ unsigned short f2bf(float x) {  // RNE
  unsigned u = __builtin_bit_cast(unsigned, x);
  u += 0x7fffu + ((u >> 16) & 1u);
  return (unsigned short)(u >> 16);
}
__device__ __forceinline__ float bf2f(unsigned short h) {
  unsigned u = ((unsigned)h) << 16;
  return __builtin_bit_cast(float, u);
}
__device__ __forceinline__ float ubit(unsigned u) { return __builtin_bit_cast(float, u); }
__device__ __forceinline__ unsigned cvt_pk_bf16(float a, float b) {  // lo=bf16(a), hi=bf16(b)
  unsigned r;
  asm("v_cvt_pk_bf16_f32 %0, %1, %2" : "=v"(r) : "v"(a), "v"(b));
  return r;
}

// ---------------- prep kernel: D (normalized), linv, lambd, A (f32) -> ws ----------------
__global__ __launch_bounds__(256) void prep_kernel(const float* __restrict__ Drr,
                                                   const float* __restrict__ Dth,
                                                   float* __restrict__ ws)
{
  __shared__ float sD[36 * 164];
  __shared__ float sIG[164];
  __shared__ float sRed[256];
  const int tid = (int)threadIdx.x;

  for (int idx = tid; idx < 36 * 164; idx += 256) {
    int t = idx / 164, k = idx - t * 164;
    float v = 0.0f;
    if (k == 0) v = 1.0f;
    else if (k < 161) {
      int km = k - 1, g = km / 40, n = km - g * 40;
      float pw  = powf(Drr[n], (float)t);
      float ang = (float)t * Dth[n];
      float base = ((g & 2) == 0) ? cosf(ang) : sinf(ang);
      v = pw * base;
      if ((g & 1) && (t & 1)) v = -v;
    }
    sD[idx] = v;
  }
  __syncthreads();
  if (tid < 161) {
    float s = 0.0f;
    for (int t = 0; t < 36; ++t) { float d = sD[t * 164 + tid]; s += d * d; }
    float g = sqrtf(s);
    if (g == 0.0f) g = 6.0f;
    sIG[tid] = 1.0f / g;
  }
  __syncthreads();
  for (int idx = tid; idx < 36 * 164; idx += 256) {
    int k = idx % 164;
    if (k < 161) sD[idx] *= sIG[k];
  }
  __syncthreads();
  {  // L = ||DtD||_F = ||D D^T||_F (36x36 gram)
    float local = 0.0f;
    for (int idx = tid; idx < 36 * 36; idx += 256) {
      int t = idx / 36, t2 = idx - t * 36;
      float dot = 0.0f;
      for (int k = 0; k < 161; ++k) dot += sD[t * 164 + k] * sD[t2 * 164 + k];
      local += dot * dot;
    }
    sRed[tid] = local;
  }
  __syncthreads();
  for (int off = 128; off > 0; off >>= 1) {
    if (tid < off) sRed[tid] += sRed[tid + off];
    __syncthreads();
  }
  const float linv = 1.0f / sqrtf(sRed[0]);

  if (blockIdx.x == 0) {
    for (int idx = tid; idx < 36 * 164; idx += 256) ws[idx] = sD[idx];
    if (tid == 0) { ws[WS_SCAL] = linv; ws[WS_SCAL + 1] = 0.01f * linv; }
  }
  const int ENT = (192 * 200 + (int)gridDim.x - 1) / (int)gridDim.x;
  const int base = (int)blockIdx.x * ENT;
  for (int i = tid; i < ENT; i += 256) {
    int e = base + i;
    if (e >= 192 * 200) break;
    int r = e / 200, j = e - r * 200;
    float a = 0.0f;
    if (r < 161 && j < 161) {
      float dot = 0.0f;
      for (int t = 0; t < 36; ++t) dot += sD[t * 164 + r] * sD[t * 164 + j];
      a = ((r == j) ? 1.0f : 0.0f) - dot * linv;
    }
    ws[WS_A + e] = a;
  }
}

// ---------------- fista kernel ----------------
union SmemU {
  struct {
    float sD[36 * 164];
    float sIG[164];
    float sRed[512];
  } su;
  unsigned char bounce[2][16 * 384];  // [buf][col*384]: d bf16, XOR-swizzled
};

// Block = 512 thr (8 waves) = 16 columns for all 100 iters.  (R4 clean shape.)
// 11 row-tiles (rows 0..175; 176..191 identically zero -> dropped):
//   waves 0..2 own tiles {2w,2w+1}; waves 3..7 own tile {3+w}.
// K-trim: MFMA covers cols 0..159 (5 K-tiles); col 160 (the only live col of the
// last tile) is a rank-1 f32 VALU update p[r] += A[r][160]*d[160]; cols 161+ are 0.
// Arch-VGPR demand ~95 (A 80 + A160 8 + misc) -- must stay <=~110: the 128-arch cap
// at 2 waves/EU caused R3/R5-R8's scratch spills (GBs of HBM traffic).
template <int USE_WS>
__global__ __launch_bounds__(512, 2) void fista_kernel(
    const float* __restrict__ X, const float* __restrict__ Drr,
    const float* __restrict__ Dth, float* __restrict__ out,
    const float* __restrict__ ws)
{
  __shared__ SmemU sm;
  float* sD = sm.su.sD;

  const int tid  = (int)threadIdx.x;
  const int lane = tid & 63;
  const int wv   = tid >> 6;     // 0..7
  const int cl   = lane & 15;    // column-in-tile / A-row-in-tile
  const int hi   = lane >> 4;    // 0..3
  const int t0   = (wv < 3) ? wv * 2 : 3 + wv;   // first owned tile
  const int ntl  = (wv < 3) ? 2 : 1;             // tiles owned

  float linv, lambd;
  if constexpr (USE_WS) {
    for (int idx = tid; idx < 36 * 164; idx += 512) sD[idx] = ws[idx];
    linv  = ws[WS_SCAL];
    lambd = ws[WS_SCAL + 1];
    __syncthreads();
  } else {
    // -------- in-block fallback --------
    for (int idx = tid; idx < 36 * 164; idx += 512) {
      int t = idx / 164, k = idx - t * 164;
      float v = 0.0f;
      if (k == 0) v = 1.0f;
      else if (k < 161) {
        int km = k - 1, g = km / 40, n = km - g * 40;
        float pw  = powf(Drr[n], (float)t);
        float ang = (float)t * Dth[n];
        float base = ((g & 2) == 0) ? cosf(ang) : sinf(ang);
        v = pw * base;
        if ((g & 1) && (t & 1)) v = -v;
      }
      sD[idx] = v;
    }
    __syncthreads();
    if (tid < 161) {
      float s = 0.0f;
      for (int t = 0; t < 36; ++t) { float d = sD[t * 164 + tid]; s += d * d; }
      float g = sqrtf(s);
      if (g == 0.0f) g = 6.0f;
      sm.su.sIG[tid] = 1.0f / g;
    }
    __syncthreads();
    for (int idx = tid; idx < 36 * 164; idx += 512) {
      int k = idx % 164;
      if (k < 161) sD[idx] *= sm.su.sIG[k];
    }
    __syncthreads();
    {
      float local = 0.0f;
      for (int idx = tid; idx < 36 * 36; idx += 512) {
        int t = idx / 36, t2 = idx - t * 36;
        float dot = 0.0f;
        for (int k = 0; k < 161; ++k) dot += sD[t * 164 + k] * sD[t2 * 164 + k];
        local += dot * dot;
      }
      sm.su.sRed[tid] = local;
    }
    __syncthreads();
    for (int off = 256; off > 0; off >>= 1) {
      if (tid < off) sm.su.sRed[tid] += sm.su.sRed[tid + off];
      __syncthreads();
    }
    linv  = 1.0f / sqrtf(sm.su.sRed[0]);
    lambd = 0.01f * linv;
  }

  // ---------- A fragments (bf16 hi/lo, cols 0..159) + f32 col-160 for owned tiles ----------
  bf16x8 Ah[MT][5], Al[MT][5];
  float a160[MT][4];
  #pragma unroll
  for (int tau = 0; tau < MT; ++tau) if (tau < ntl) {
    const int r = (t0 + tau) * 16 + cl;
    #pragma unroll
    for (int kt = 0; kt < 5; ++kt) {
      const int k0 = kt * 32 + hi * 8;
      float av[8];
      if constexpr (USE_WS) {
        const float* ap = ws + WS_A + r * 200 + k0;
        f32x4 a0 = *reinterpret_cast<const f32x4*>(ap);
        f32x4 a1 = *reinterpret_cast<const f32x4*>(ap + 4);
        av[0]=a0[0]; av[1]=a0[1]; av[2]=a0[2]; av[3]=a0[3];
        av[4]=a1[0]; av[5]=a1[1]; av[6]=a1[2]; av[7]=a1[3];
      } else {
        float acc8[8];
        #pragma unroll
        for (int j = 0; j < 8; ++j) acc8[j] = 0.0f;
        if (r < 161) {
          for (int t = 0; t < 36; ++t) {
            float vr = sD[t * 164 + r];
            #pragma unroll
            for (int j = 0; j < 8; ++j) acc8[j] += vr * sD[t * 164 + k0 + j];
          }
        }
        #pragma unroll
        for (int j = 0; j < 8; ++j) {
          int k = k0 + j;
          float a = 0.0f;
          if (r < 161 && k < 161) {
            a = -acc8[j] * linv;
            if (r == k) a += 1.0f;
          }
          av[j] = a;
        }
      }
      bf16x8 vh, vl;
      #pragma unroll
      for (int j = 0; j < 8; ++j) {
        unsigned short h = f2bf(av[j]);
        vh[j] = (short)h;
        vl[j] = (short)f2bf(av[j] - bf2f(h));
      }
      Ah[tau][kt] = vh;
      Al[tau][kt] = vl;
    }
    // f32 column 160 for this wave's 4 rows (per q): rows rq = (t0+tau)*16 + hi*4 + q
    #pragma unroll
    for (int q = 0; q < 4; ++q) {
      const int rq = (t0 + tau) * 16 + hi * 4 + q;
      if constexpr (USE_WS) {
        a160[tau][q] = ws[WS_A + rq * 200 + 160];
      } else {
        float a = 0.0f;
        if (rq < 161) {
          float dot = 0.0f;
          for (int t = 0; t < 36; ++t) dot += sD[t * 164 + rq] * sD[t * 164 + 160];
          a = ((rq == 160) ? 1.0f : 0.0f) - dot * linv;
        }
        a160[tau][q] = a;
      }
    }
  }
  #pragma unroll
  for (int tau = 0; tau < MT; ++tau) if (tau >= ntl)
    #pragma unroll
    for (int q = 0; q < 4; ++q) a160[tau][q] = 0.0f;

  // ---------- DtY -> P0 (C/D layout: row=(t0+tau)*16+hi*4+q, col=cl) ----------
  const int c = (int)blockIdx.x * 16 + cl;
  const int b = c >> 14;
  const int p = c & 16383;
  const float* Xc = X + (size_t)b * (36 * 16384) + p;

  f32x4 P0[MT], P1[MT], xe[MT];
  #pragma unroll
  for (int tau = 0; tau < MT; ++tau)
    #pragma unroll
    for (int q = 0; q < 4; ++q) { P0[tau][q] = 0.0f; P1[tau][q] = 0.0f; xe[tau][q] = 0.0f; }

  for (int t = 0; t < 36; ++t) {
    float yv = Xc[(size_t)t * 16384];
    #pragma unroll
    for (int tau = 0; tau < MT; ++tau) if (tau < ntl) {
      const int rt = t0 + tau;
      f32x4 df = *reinterpret_cast<const f32x4*>(sD + t * 164 + rt * 16 + hi * 4);
      #pragma unroll
      for (int q = 0; q < 4; ++q) P0[tau][q] += df[q] * yv;
    }
  }
  #pragma unroll
  for (int tau = 0; tau < MT; ++tau)
    #pragma unroll
    for (int q = 0; q < 4; ++q) {
      int r = (t0 + tau) * 16 + hi * 4 + q;
      P0[tau][q] = (r < 161) ? P0[tau][q] * linv : 0.0f;
    }
  __syncthreads();   // sD dead; zero the bounce buffers

  for (int i = tid; i < 2 * 16 * 384 / 16; i += 512) {
    f32x4 z = {0.0f, 0.0f, 0.0f, 0.0f};
    reinterpret_cast<f32x4*>(sm.bounce[0])[i] = z;
  }
  __syncthreads();

  // ---------- precomputed swizzled LDS addresses ----------
  unsigned char* colb = sm.bounce[0] + cl * 384;
  const unsigned swz = (unsigned)((cl & 7) << 4);
  unsigned char* rdA[5];
  #pragma unroll
  for (int kt = 0; kt < 5; ++kt)
    rdA[kt] = colb + (((unsigned)(kt * 64 + hi * 16)) ^ swz);
  unsigned char* rd160 = colb + (320u ^ swz);      // d[160] (bf16, byte 320 pre-swizzle)
  unsigned char* wrA[MT];
  #pragma unroll
  for (int tau = 0; tau < MT; ++tau)
    wrA[tau] = colb + (((unsigned)((t0 + tau) * 32 + hi * 8)) ^ swz);

  // ---------- FISTA main loop ----------
  float tcur = 1.0f, tt = 0.0f;

  // p tracks A*xe + DtY (xe = running sum of quantized increments, error feedback).
  // u = (1+tt)p_k - tt p_{k-1}; xn = shrink(u); dq = bf16(xn - xe); xe += dq;
  // p_{k+1} = p_k + (Ah+Al)*dq[0..159]  (MFMA)  + A[:,160]*dq[160]  (f32 rank-1).
  auto step = [&](f32x4 (&PC)[MT], f32x4 (&PN)[MT], int boff) {
    const float ttp = tt, c1 = 1.0f + ttp;
    #pragma unroll
    for (int tau = 0; tau < MT; ++tau) if (tau < ntl) {
      float dq_[4];
      #pragma unroll
      for (int q = 0; q < 4; ++q) {
        float u  = c1 * PC[tau][q] - ttp * PN[tau][q];
        float aa = fmaxf(fabsf(u) - lambd, 0.0f);
        float xn = __builtin_copysignf(aa, u);
        dq_[q] = xn - xe[tau][q];
      }
      unsigned w0 = cvt_pk_bf16(dq_[0], dq_[1]);
      unsigned w1 = cvt_pk_bf16(dq_[2], dq_[3]);
      xe[tau][0] += ubit(w0 << 16);
      xe[tau][1] += ubit(w0 & 0xffff0000u);
      xe[tau][2] += ubit(w1 << 16);
      xe[tau][3] += ubit(w1 & 0xffff0000u);
      *reinterpret_cast<uint2*>(wrA[tau] + boff) = make_uint2(w0, w1);
    }
    __syncthreads();   // d visible; double-buffer -> 1 barrier/step
    const float d160 = ubit((unsigned)*reinterpret_cast<const unsigned short*>(rd160 + boff) << 16);
    bf16x8 bh[5];
    #pragma unroll
    for (int kt = 0; kt < 5; ++kt)
      bh[kt] = *reinterpret_cast<const bf16x8*>(rdA[kt] + boff);
    #pragma unroll
    for (int kt = 0; kt < 5; ++kt) {
      #pragma unroll
      for (int tau = 0; tau < MT; ++tau) if (tau < ntl) {
        f32x4 acc = (kt == 0) ? PC[tau] : PN[tau];
        acc = __builtin_amdgcn_mfma_f32_16x16x32_bf16(Ah[tau][kt], bh[kt], acc, 0, 0, 0);
        acc = __builtin_amdgcn_mfma_f32_16x16x32_bf16(Al[tau][kt], bh[kt], acc, 0, 0, 0);
        PN[tau] = acc;   // partial p_{k+1}
      }
    }
    #pragma unroll
    for (int tau = 0; tau < MT; ++tau) if (tau < ntl)
      #pragma unroll
      for (int q = 0; q < 4; ++q)
        PN[tau][q] += a160[tau][q] * d160;   // col-160 rank-1 (f32 exact)
    const float tn = 0.5f * (1.0f + sqrtf(1.0f + 4.0f * tcur * tcur));
    tt = (tcur - 1.0f) / tn;
    tcur = tn;
  };

  #pragma unroll 1
  for (int it = 0; it < NITER / 2; ++it) {
    step(P0, P1, 0);
    step(P1, P0, 16 * 384);
  }

  // ---------- store x (= xe) ----------
  float* op = out + (size_t)b * (161 * 16384) + p;
  #pragma unroll
  for (int tau = 0; tau < MT; ++tau) if (tau < ntl) {
    #pragma unroll
    for (int q = 0; q < 4; ++q) {
      int r = (t0 + tau) * 16 + hi * 4 + q;
      if (r < 161) op[(size_t)r * 16384] = xe[tau][q];
    }
  }
}

extern "C" void kernel_launch(void* const* d_in, const int* in_sizes, int n_in,
                              void* d_out, int out_size, void* d_ws, size_t ws_size,
                              hipStream_t stream) {
  const float* X   = (const float*)d_in[0];
  const float* Drr = (const float*)d_in[1];
  const float* Dth = (const float*)d_in[2];
  float* out = (float*)d_out;
  (void)in_sizes; (void)n_in; (void)out_size;

  if (ws_size >= (size_t)WS_FLOATS * sizeof(float)) {
    float* ws = (float*)d_ws;
    prep_kernel<<<dim3(64), dim3(256), 0, stream>>>(Drr, Dth, ws);
    fista_kernel<1><<<dim3(4096), dim3(512), 0, stream>>>(X, Drr, Dth, out, ws);
  } else {
    fista_kernel<0><<<dim3(4096), dim3(512), 0, stream>>>(X, Drr, Dth, out, nullptr);
  }
}